// Round 4
// baseline (825.353 us; speedup 1.0000x reference)
//
#include <hip/hip_runtime.h>
#include <stdint.h>

typedef __bf16 bf16x8 __attribute__((ext_vector_type(8)));
typedef float  f32x4  __attribute__((ext_vector_type(4)));

#define MFMA16(a, b, c) __builtin_amdgcn_mfma_f32_16x16x32_bf16((a), (b), (c), 0, 0, 0)

static constexpr int   kBz = 64, kNn = 577, kEe = 768, kHh = 8, kDd = 96;
static constexpr int   kM  = kBz * kNn;  // 36928 tokens
static constexpr float kScale = 0.10206207261596575f;  // 96^-0.5

__device__ __forceinline__ unsigned short f2bf(float f) {
  unsigned u = __float_as_uint(f);
  u += 0x7fffu + ((u >> 16) & 1u);  // RNE
  return (unsigned short)(u >> 16);
}
__device__ __forceinline__ float bf2f(unsigned short s) {
  return __uint_as_float(((unsigned)s) << 16);
}

__device__ __forceinline__ void gload16(const void* g, void* l) {
  __builtin_amdgcn_global_load_lds(
      (const __attribute__((address_space(1))) void*)(void*)g,
      (__attribute__((address_space(3))) void*)l, 16, 0, 0);
}

// ---------------- kernel 1: split x into bf16 hi/lo ----------------
__global__ __launch_bounds__(256) void k_castx(const float* __restrict__ x,
                                               unsigned short* __restrict__ xh,
                                               unsigned short* __restrict__ xl) {
  const int i = blockIdx.x * 256 + threadIdx.x;
  if (i >= kM * kEe / 4) return;
  const float4 v = reinterpret_cast<const float4*>(x)[i];
  float f[4] = {v.x, v.y, v.z, v.w};
  ushort4 h, lo;
  unsigned short hs[4], ls[4];
#pragma unroll
  for (int j = 0; j < 4; ++j) {
    hs[j] = f2bf(f[j]);
    ls[j] = f2bf(f[j] - bf2f(hs[j]));
  }
  h.x = hs[0]; h.y = hs[1]; h.z = hs[2]; h.w = hs[3];
  lo.x = ls[0]; lo.y = ls[1]; lo.z = ls[2]; lo.w = ls[3];
  reinterpret_cast<ushort4*>(xh)[i] = h;
  reinterpret_cast<ushort4*>(xl)[i] = lo;
}

// ------- kernel 2: build W^T concat [3*768 n][2304 k] = [hi | lo | hi] -------
__global__ __launch_bounds__(256) void k_wcat(const float* __restrict__ Wq,
                                              const float* __restrict__ Wk,
                                              const float* __restrict__ Wv,
                                              unsigned short* __restrict__ wcat) {
  const int o = blockIdx.x * 256 + threadIdx.x;
  if (o >= 3 * 768 * 2304) return;
  const int gn = o / 2304, ks = o - gn * 2304;
  const int seg = ks / 768, k = ks - seg * 768;
  const int mat = gn / 768, n = gn - mat * 768;
  const float* W = (mat == 0) ? Wq : ((mat == 1) ? Wk : Wv);
  const float v = W[k * 768 + n];  // W is [k][n] row-major
  const unsigned short h = f2bf(v);
  wcat[o] = (seg == 1) ? f2bf(v - bf2f(h)) : h;
}

// ------- kernel 3: QKV projection GEMM, m201-faithful 8-phase schedule -------
// A = [xh | xh | xl] (M=36928, K=2304), B = wcat rows (N=2304, K=2304).
// 8 waves (2M x 4N), per-wave 128x64 output. 2 K-tiles/iter: even->S0, odd->S1.
// Per phase: {ds-reads (quadrant-reuse 00,01,11,10) | one 2-gload stage unit |
// barrier | lgkmcnt(0) | setprio(1) 16xMFMA setprio(0) | [vmcnt(6) @P4/P8] |
// barrier}. All LDS read addrs hoisted; phase offsets are ds-offset immediates.
struct ProjArgs {
  const unsigned short* xh; const unsigned short* xl; const unsigned short* wcat;
};

#define MIDSYNC do { __builtin_amdgcn_s_barrier(); \
  asm volatile("s_waitcnt lgkmcnt(0)" ::: "memory"); \
  __builtin_amdgcn_sched_barrier(0); \
  __builtin_amdgcn_s_setprio(1); } while (0)
#define ENDPH do { __builtin_amdgcn_s_setprio(0); \
  __builtin_amdgcn_s_barrier(); \
  __builtin_amdgcn_sched_barrier(0); } while (0)
#define ENDPH_VM6 do { __builtin_amdgcn_s_setprio(0); \
  asm volatile("s_waitcnt vmcnt(6)" ::: "memory"); \
  __builtin_amdgcn_s_barrier(); \
  __builtin_amdgcn_sched_barrier(0); } while (0)
#define ENDPH_VM0 do { __builtin_amdgcn_s_setprio(0); \
  asm volatile("s_waitcnt vmcnt(0)" ::: "memory"); \
  __builtin_amdgcn_s_barrier(); \
  __builtin_amdgcn_sched_barrier(0); } while (0)

__global__ __launch_bounds__(512, 2) void k_proj(
    const unsigned short* __restrict__ xh, const unsigned short* __restrict__ xl,
    const unsigned short* __restrict__ wcat,
    const float* __restrict__ bq, const float* __restrict__ bk, const float* __restrict__ bv,
    unsigned short* __restrict__ Qh, unsigned short* __restrict__ Ql,
    unsigned short* __restrict__ Kh, unsigned short* __restrict__ Kl,
    unsigned short* __restrict__ V) {
  extern __shared__ char smem[];  // 131072 B: A S0@0 S1@32768, B S0@65536 S1@98304
  const int tid = threadIdx.x, w = tid >> 6, l = tid & 63;
  const int wm = w >> 2, wn = w & 3;

  // bijective XCD swizzle: nwg=1305, q=163, r=1
  int bid = blockIdx.x;
  {
    const int xcd = bid & 7, i = bid >> 3;
    bid = ((xcd < 1) ? xcd * 164 : 164 + (xcd - 1) * 163) + i;
  }
  const int ntile = bid % 9, mtile = bid / 9;

  const int lrow8 = l >> 3;
  const int lc_sw = (l & 7) ^ lrow8;

  // stage slot ids: 2 per wave per unit
  const int p0 = 2 * w, p1 = 2 * w + 1;
  int gAq[2][2], gBq[2][2];
  gAq[0][0] = (w < 4) ? 2 * w : 16 + 2 * (w - 4);
  gAq[0][1] = gAq[0][0] + 1;
  gAq[1][0] = gAq[0][0] + 8;
  gAq[1][1] = gAq[0][1] + 8;
  gBq[0][0] = (p0 >> 2) * 8 + (p0 & 3);
  gBq[0][1] = (p1 >> 2) * 8 + (p1 & 3);
  gBq[1][0] = gBq[0][0] + 4;
  gBq[1][1] = gBq[0][1] + 4;

  // hoisted global byte-voffsets
  unsigned voffA[2][2], voffB[2][2];
#pragma unroll
  for (int h = 0; h < 2; ++h)
#pragma unroll
    for (int j = 0; j < 2; ++j) {
      int m = mtile * 256 + 8 * gAq[h][j] + lrow8;
      if (m > kM - 1) m = kM - 1;
      voffA[h][j] = (unsigned)(m * 1536 + lc_sw * 16);
      const int bn = ntile * 256 + 8 * gBq[h][j] + lrow8;
      voffB[h][j] = (unsigned)(bn * 4608 + lc_sw * 16);
    }

  // hoisted LDS read base pointers [half][ks]
  const char* rdA[2][2];
  const char* rdB[2][2];
#pragma unroll
  for (int ks = 0; ks < 2; ++ks) {
    const int cks = (((ks * 4) + (l >> 4)) ^ (l & 7)) * 16;
#pragma unroll
    for (int h = 0; h < 2; ++h) {
      rdA[h][ks] = smem + (wm * 128 + h * 64 + (l & 15)) * 128 + cks;
      rdB[h][ks] = smem + 65536 + (wn * 64 + h * 32 + (l & 15)) * 128 + cks;
    }
  }

  const char* xbase = (const char*)xh;   // xl contiguous at +56721408
  const char* wbase = (const char*)wcat;

  f32x4 acc[8][4];
  const f32x4 fz = {0.f, 0.f, 0.f, 0.f};
#pragma unroll
  for (int i = 0; i < 8; ++i)
#pragma unroll
    for (int j = 0; j < 4; ++j) acc[i][j] = fz;

  bf16x8 af[4][2], bf[2][2];

  auto stA = [&](int Sb, int mh, unsigned koff) {
    gload16(xbase + koff + voffA[mh][0], smem + Sb + gAq[mh][0] * 1024);
    gload16(xbase + koff + voffA[mh][1], smem + Sb + gAq[mh][1] * 1024);
  };
  auto stB = [&](int Sb, int nh, unsigned koff) {
    gload16(wbase + koff + voffB[nh][0], smem + 65536 + Sb + gBq[nh][0] * 1024);
    gload16(wbase + koff + voffB[nh][1], smem + 65536 + Sb + gBq[nh][1] * 1024);
  };
  auto rdAf = [&](int Sb, int mh) {
#pragma unroll
    for (int mi4 = 0; mi4 < 4; ++mi4) {
      af[mi4][0] = *reinterpret_cast<const bf16x8*>(rdA[mh][0] + Sb + mi4 * 2048);
      af[mi4][1] = *reinterpret_cast<const bf16x8*>(rdA[mh][1] + Sb + mi4 * 2048);
    }
  };
  auto rdBf = [&](int Sb, int nh) {
#pragma unroll
    for (int ni2 = 0; ni2 < 2; ++ni2) {
      bf[ni2][0] = *reinterpret_cast<const bf16x8*>(rdB[nh][0] + Sb + ni2 * 2048);
      bf[ni2][1] = *reinterpret_cast<const bf16x8*>(rdB[nh][1] + Sb + ni2 * 2048);
    }
  };
  auto mfmaQ = [&](int mh, int nh) {
#pragma unroll
    for (int mi4 = 0; mi4 < 4; ++mi4)
#pragma unroll
      for (int ni2 = 0; ni2 < 2; ++ni2)
#pragma unroll
        for (int ks = 0; ks < 2; ++ks)
          acc[mh * 4 + mi4][nh * 2 + ni2] =
              MFMA16(af[mi4][ks], bf[ni2][ks], acc[mh * 4 + mi4][nh * 2 + ni2]);
  };
  auto akoff = [](int t) -> unsigned {
    return (unsigned)((t % 12) * 128) + (t >= 24 ? 56721408u : 0u);
  };

  // ---- prologue: t0 all 4 units + t1 {A0,B1,A1}; vmcnt(6) leaves t1's 3 in flight
  stA(0, 0, akoff(0));
  stB(0, 1, 0);
  stA(0, 1, akoff(0));
  stB(0, 0, 0);
  stA(32768, 0, akoff(1));
  stB(32768, 1, 128);
  stA(32768, 1, akoff(1));
  asm volatile("s_waitcnt vmcnt(6)" ::: "memory");
  __builtin_amdgcn_s_barrier();
  __builtin_amdgcn_sched_barrier(0);

  // ---- main loop: 18 iterations x 2 K-tiles, 8 phases each ----
  for (int i = 0; i < 18; ++i) {
    const bool nf = (i < 17);
    const unsigned kB1 = (unsigned)((2 * i + 1) * 128);
    const unsigned kA2 = akoff(2 * i + 2);
    const unsigned kB2 = (unsigned)((2 * i + 2) * 128);
    const unsigned kA3 = akoff(2 * i + 3);
    const unsigned kB3 = (unsigned)((2 * i + 3) * 128);

    // P1: tile even Q(0,0); stage B0(odd)->S1
    rdAf(0, 0); rdBf(0, 0); stB(32768, 0, kB1);
    MIDSYNC; mfmaQ(0, 0); ENDPH;
    // P2: Q(0,1); stage A0(even+2)->S0
    rdBf(0, 1); if (nf) stA(0, 0, kA2);
    MIDSYNC; mfmaQ(0, 1); ENDPH;
    // P3: Q(1,1); stage B1(even+2)->S0
    rdAf(0, 1); if (nf) stB(0, 1, kB2);
    MIDSYNC; mfmaQ(1, 1); ENDPH;
    // P4: Q(1,0); stage A1(even+2)->S0; counted vmcnt
    rdBf(0, 0); if (nf) stA(0, 1, kA2);
    MIDSYNC; mfmaQ(1, 0);
    if (nf) { ENDPH_VM6; } else { ENDPH_VM0; }
    // P5: tile odd Q(0,0); stage B0(even+2)->S0
    rdAf(32768, 0); rdBf(32768, 0); if (nf) stB(0, 0, kB2);
    MIDSYNC; mfmaQ(0, 0); ENDPH;
    // P6: Q(0,1); stage A0(odd+2)->S1
    rdBf(32768, 1); if (nf) stA(32768, 0, kA3);
    MIDSYNC; mfmaQ(0, 1); ENDPH;
    // P7: Q(1,1); stage B1(odd+2)->S1
    rdAf(32768, 1); if (nf) stB(32768, 1, kB3);
    MIDSYNC; mfmaQ(1, 1); ENDPH;
    // P8: Q(1,0); stage A1(odd+2)->S1; counted vmcnt
    rdBf(32768, 0); if (nf) stA(32768, 1, kA3);
    MIDSYNC; mfmaQ(1, 0);
    if (nf) { ENDPH_VM6; } else { ENDPH_VM0; }
  }

  // ---- epilogue: bias add, split to bf16 hi/lo, write [B,H,N,D] ----
  const int matrix = ntile / 3;  // 0=Q 1=K 2=V (256 | 768, so no tile crosses)
  const float* bias = (matrix == 0) ? bq : ((matrix == 1) ? bk : bv);
  int hh[4], dd[4];
  float bb[4];
#pragma unroll
  for (int ni = 0; ni < 4; ++ni) {
    const int n_in = (ntile % 3) * 256 + wn * 64 + ni * 16 + (l & 15);
    hh[ni] = n_in / 96;
    dd[ni] = n_in - hh[ni] * 96;
    bb[ni] = bias[n_in];
  }
#pragma unroll
  for (int mi = 0; mi < 8; ++mi) {
#pragma unroll
    for (int r = 0; r < 4; ++r) {
      const int m = mtile * 256 + wm * 128 + mi * 16 + (l >> 4) * 4 + r;
      if (m >= kM) continue;
      const int bidx = m / 577;
      const int n = m - bidx * 577;
#pragma unroll
      for (int ni = 0; ni < 4; ++ni) {
        const float val = acc[mi][ni][r] + bb[ni];
        const size_t o = ((size_t)(bidx * 8 + hh[ni]) * 577 + n) * 96 + dd[ni];
        if (matrix == 0) {
          const unsigned short hi = f2bf(val);
          Qh[o] = hi; Ql[o] = f2bf(val - bf2f(hi));
        } else if (matrix == 1) {
          const unsigned short hi = f2bf(val);
          Kh[o] = hi; Kl[o] = f2bf(val - bf2f(hi));
        } else {
          V[o] = f2bf(val);
        }
      }
    }
  }
}

// ---------------- kernel 4: V [bh][577][96] -> V^T [bh][96][640] ----------------
__global__ __launch_bounds__(256) void k_vt(const unsigned short* __restrict__ V,
                                            unsigned short* __restrict__ Vt) {
  __shared__ unsigned int Tu[32][49];
  const int nt = blockIdx.x, bh = blockIdx.y;
  const int t = threadIdx.x;
  const unsigned int* Vu = reinterpret_cast<const unsigned int*>(V);
  unsigned int* Vtu = reinterpret_cast<unsigned int*>(Vt);
  const int n0 = nt * 32;
#pragma unroll
  for (int i = 0; i < 6; ++i) {
    const int u = t + i * 256;  // < 1536
    const int ln = u / 48, cu = u - ln * 48;
    int n = n0 + ln; if (n > 576) n = 576;
    Tu[ln][cu] = Vu[(size_t)(bh * 577 + n) * 48 + cu];
  }
  __syncthreads();
#pragma unroll
  for (int i = 0; i < 6; ++i) {
    const int u = t + i * 256;
    const int d = u / 16, cu = u - d * 16;
    const unsigned int w0 = Tu[2 * cu][d >> 1];
    const unsigned int w1 = Tu[2 * cu + 1][d >> 1];
    const int sh = (d & 1) * 16;
    Vtu[(size_t)(bh * 96 + d) * 320 + nt * 16 + cu] =
        ((w0 >> sh) & 0xffffu) | (((w1 >> sh) & 0xffffu) << 16);
  }
}

// ---------------- kernel 5: fused flash attention ----------------
__global__ __launch_bounds__(256) void k_attn(
    const unsigned short* __restrict__ Qh, const unsigned short* __restrict__ Ql,
    const unsigned short* __restrict__ Kh, const unsigned short* __restrict__ Kl,
    const unsigned short* __restrict__ Vt, float* __restrict__ out) {
  __shared__ __align__(16) char sKH[16384];   // [64 kv][128 bf16 rows=256B], swizzled
  __shared__ __align__(16) char sKL[16384];
  __shared__ __align__(16) char sVT[12288];   // [96 d][64 bf16 = 128B], swizzled
  __shared__ __align__(16) char sP[4][2304];  // per-wave P: [16 q][72 bf16 = 144B]
  const int qt = blockIdx.x, bh = blockIdx.y;
  const int tid = threadIdx.x, w = tid >> 6, l = tid & 63;
  const int bb_ = bh >> 3, hh_ = bh & 7;
  const size_t hdbase = (size_t)bh * 577 * 96;

  const int qrow = qt * 64 + w * 16 + (l & 15);
  const int qn = (qrow > 576) ? 576 : qrow;

  // Q hoisted to registers: B-operand frags (hi/lo) for 3 d-ksteps
  bf16x8 fqh[3], fql[3];
#pragma unroll
  for (int ks = 0; ks < 3; ++ks) {
    const size_t off = hdbase + (size_t)qn * 96 + ks * 32 + (l >> 4) * 8;
    fqh[ks] = *reinterpret_cast<const bf16x8*>(Qh + off);
    fql[ks] = *reinterpret_cast<const bf16x8*>(Ql + off);
  }

  f32x4 accO[6];
  const f32x4 fz = {0.f, 0.f, 0.f, 0.f};
#pragma unroll
  for (int i = 0; i < 6; ++i) accO[i] = fz;
  float mrun = -1e30f, lrun = 0.f;

  for (int kt = 0; kt < 10; ++kt) {
    // ---- stage K hi/lo + V^T tiles (44 x 1KB gload_lds, 11 per wave) ----
#pragma unroll
    for (int i = 0; i < 11; ++i) {
      const int j = w * 11 + i;
      if (j < 32) {
        const int jj = j & 15;
        const int r = 4 * jj + (l >> 4);
        const int lc = (l & 15) ^ (r & 7);
        const int lc2 = (lc < 12) ? lc : 11;
        int kvn = kt * 64 + r; if (kvn > 576) kvn = 576;
        const unsigned short* src = (j < 16) ? Kh : Kl;
        char* dst = (j < 16) ? (sKH + jj * 1024) : (sKL + jj * 1024);
        gload16(src + hdbase + (size_t)kvn * 96 + lc2 * 8, dst);
      } else {
        const int j2 = j - 32;
        const int d = 8 * j2 + (l >> 3);
        const int lc = (l & 7) ^ (d & 7);
        gload16(Vt + (size_t)(bh * 96 + d) * 640 + kt * 64 + lc * 8, sVT + j2 * 1024);
      }
    }
    __syncthreads();

    // ---- S^T = K · Q^T, 3-term bf16x2 split ----
    f32x4 s_[4];
#pragma unroll
    for (int i = 0; i < 4; ++i) s_[i] = fz;
#pragma unroll
    for (int ks = 0; ks < 3; ++ks) {
#pragma unroll
      for (int af = 0; af < 4; ++af) {
        const int r = af * 16 + (l & 15);
        const int c16 = ((ks * 4) + (l >> 4)) ^ (r & 7);
        const bf16x8 kh = *reinterpret_cast<const bf16x8*>(sKH + r * 256 + c16 * 16);
        const bf16x8 kl = *reinterpret_cast<const bf16x8*>(sKL + r * 256 + c16 * 16);
        s_[af] = MFMA16(kh, fqh[ks], s_[af]);
        s_[af] = MFMA16(kh, fql[ks], s_[af]);
        s_[af] = MFMA16(kl, fqh[ks], s_[af]);
      }
    }

    if (kt == 9) {  // mask kv >= 577
#pragma unroll
      for (int af = 0; af < 4; ++af) {
        const int kv0 = 576 + af * 16 + (l >> 4) * 4;
#pragma unroll
        for (int r = 0; r < 4; ++r)
          if (kv0 + r >= 577) s_[af][r] = -1e30f;
      }
    }

    // ---- online softmax (lane holds 16 kv of its q-row; reduce over 4 lanes) ----
    float pmax = -1e30f;
#pragma unroll
    for (int af = 0; af < 4; ++af)
#pragma unroll
      for (int r = 0; r < 4; ++r) pmax = fmaxf(pmax, s_[af][r]);
    pmax = fmaxf(pmax, __shfl_xor(pmax, 16, 64));
    pmax = fmaxf(pmax, __shfl_xor(pmax, 32, 64));
    const float mnew = fmaxf(mrun, pmax);
    const float fsc = __expf(mrun - mnew);
    float psum = 0.f;
    char* pbase = sP[w] + (l & 15) * 144;
#pragma unroll
    for (int af = 0; af < 4; ++af) {
      const float p0 = __expf(s_[af][0] - mnew);
      const float p1 = __expf(s_[af][1] - mnew);
      const float p2 = __expf(s_[af][2] - mnew);
      const float p3 = __expf(s_[af][3] - mnew);
      psum += (p0 + p1) + (p2 + p3);
      const unsigned w0 = (unsigned)f2bf(p0) | ((unsigned)f2bf(p1) << 16);
      const unsigned w1 = (unsigned)f2bf(p2) | ((unsigned)f2bf(p3) << 16);
      *reinterpret_cast<unsigned*>(pbase + af * 32 + (l >> 4) * 8) = w0;
      *reinterpret_cast<unsigned*>(pbase + af * 32 + (l >> 4) * 8 + 4) = w1;
    }
    psum += __shfl_xor(psum, 16, 64);
    psum += __shfl_xor(psum, 32, 64);
    lrun = lrun * fsc + psum;
    mrun = mnew;
#pragma unroll
    for (int i = 0; i < 6; ++i)
#pragma unroll
      for (int r = 0; r < 4; ++r) accO[i][r] *= fsc;
    __syncthreads();  // cross-lane P visibility

    // ---- O^T += V^T · P^T ----
#pragma unroll
    for (int ks = 0; ks < 2; ++ks) {
      const bf16x8 pb = *reinterpret_cast<const bf16x8*>(
          sP[w] + (l & 15) * 144 + ks * 64 + (l >> 4) * 16);
#pragma unroll
      for (int df = 0; df < 6; ++df) {
        const int r = df * 16 + (l & 15);
        const int c16 = ((ks * 4) + (l >> 4)) ^ (r & 7);
        const bf16x8 va = *reinterpret_cast<const bf16x8*>(sVT + r * 128 + c16 * 16);
        accO[df] = MFMA16(va, pb, accO[df]);
      }
    }
    __syncthreads();  // reads done before next stage overwrites
  }

  // ---- epilogue: out[b][n][h*96+d] = O * scale / l ----
  if (qrow <= 576) {
    const float inv = kScale / lrun;
#pragma unroll
    for (int df = 0; df < 6; ++df) {
      float4 o;
      o.x = accO[df][0] * inv; o.y = accO[df][1] * inv;
      o.z = accO[df][2] * inv; o.w = accO[df][3] * inv;
      const size_t oo = ((size_t)bb_ * 577 + qrow) * 768 + hh_ * 96 + df * 16 + (l >> 4) * 4;
      *reinterpret_cast<float4*>(out + oo) = o;
    }
  }
}

extern "C" void kernel_launch(void* const* d_in, const int* in_sizes, int n_in,
                              void* d_out, int out_size, void* d_ws, size_t ws_size,
                              hipStream_t stream) {
  const float* x  = (const float*)d_in[0];
  const float* Wq = (const float*)d_in[1];
  const float* bq = (const float*)d_in[2];
  const float* Wk = (const float*)d_in[3];
  const float* bk = (const float*)d_in[4];
  const float* Wv = (const float*)d_in[5];
  const float* bv = (const float*)d_in[6];
  float* out = (float*)d_out;
  char* ws = (char*)d_ws;

  const size_t SZ = 56721408;  // 36928*768*2 == 512*577*96*2 bytes
  unsigned short* xh   = (unsigned short*)(ws);
  unsigned short* xl   = (unsigned short*)(ws + SZ);  // MUST stay contiguous after xh
  unsigned short* wcat = (unsigned short*)(ws + 2 * SZ);
  unsigned short* Qh   = (unsigned short*)(ws + 2 * SZ + 10616832);
  unsigned short* Ql   = (unsigned short*)(ws + 3 * SZ + 10616832);
  unsigned short* Kh   = (unsigned short*)(ws + 4 * SZ + 10616832);
  unsigned short* Kl   = (unsigned short*)(ws + 5 * SZ + 10616832);
  unsigned short* V    = (unsigned short*)(ws + 6 * SZ + 10616832);
  unsigned short* Vt   = (unsigned short*)(ws);  // aliases xh/xl (dead after k_proj)

  hipFuncSetAttribute((const void*)k_proj,
                      hipFuncAttributeMaxDynamicSharedMemorySize, 131072);

  k_castx<<<27696, 256, 0, stream>>>(x, xh, xl);
  k_wcat<<<20736, 256, 0, stream>>>(Wq, Wk, Wv, wcat);
  k_proj<<<dim3(1305), 512, 131072, stream>>>(xh, xl, wcat, bq, bk, bv, Qh, Ql, Kh, Kl, V);
  k_vt<<<dim3(20, 512), 256, 0, stream>>>(V, Vt);
  k_attn<<<dim3(10, 512), 256, 0, stream>>>(Qh, Ql, Kh, Kl, Vt, out);
}